// Round 8
// baseline (305.575 us; speedup 1.0000x reference)
//
#include <hip/hip_runtime.h>
#include <hip/hip_fp16.h>

#define NN 65536
#define EE 524288
#define CC 128
#define CAP 40    // bucket capacity; P(deg>=40) ~ 1e-15 at lambda=8
#define CSH 4     // cnt stride shift: 16 ints = one 64B line per counter

typedef _Float16 f16x8 __attribute__((ext_vector_type(8)));
typedef float f32x4 __attribute__((ext_vector_type(4)));

// ---------- k_init: convert+stats | bucket scatter | weight transpose (fp32) ----------
__global__ void k_init(const float* __restrict__ x, __half* __restrict__ h,
                       float* __restrict__ pstat0,
                       const int* __restrict__ src, const int* __restrict__ dst,
                       const float* __restrict__ ew,
                       int* __restrict__ cnt, unsigned int* __restrict__ buf,
                       const float* __restrict__ Ws, const float* __restrict__ Wn,
                       float* __restrict__ Wt) {
    __shared__ float smemF[64 * 128];   // 32 KB: transpose tile / convert reduction
    int b = blockIdx.x, t = threadIdx.x;
    if (b < 256) {
        const float4* xv = (const float4*)x;
        __half2* o = (__half2*)h;
        float s[4] = {0, 0, 0, 0}, q[4] = {0, 0, 0, 0};
        for (int k = 0; k < 32; k++) {
            int i = b * 8192 + k * 256 + t;
            float4 v = xv[i];
            o[2 * i]     = __floats2half2_rn(v.x, v.y);
            o[2 * i + 1] = __floats2half2_rn(v.z, v.w);
            s[0] += v.x; s[1] += v.y; s[2] += v.z; s[3] += v.w;
            q[0] += v.x * v.x; q[1] += v.y * v.y; q[2] += v.z * v.z; q[3] += v.w * v.w;
        }
        float* ls = smemF;               // [0..127] sum, [128..255] sumsq
        ls[t] = 0.f;
        __syncthreads();
        int c0 = (t & 31) * 4;
#pragma unroll
        for (int u = 0; u < 4; u++) {
            atomicAdd(&ls[c0 + u], s[u]);
            atomicAdd(&ls[128 + c0 + u], q[u]);
        }
        __syncthreads();
        if (t < 128) {
            atomicAdd(&pstat0[t], ls[t]);
            atomicAdd(&pstat0[128 + t], ls[128 + t]);
        }
    } else if (b < 256 + EE / 256) {
        int e = (b - 256) * 256 + t;
        int d = dst[e];
        int pos = atomicAdd(&cnt[d << CSH], 1);
        float w = log1pf(ew[e]);
        unsigned int pk = (unsigned int)src[e] |
                          ((unsigned int)__half_as_ushort(__float2half(w)) << 16);
        if (pos < CAP) buf[(size_t)d * CAP + pos] = pk;
    } else {
        int tb = b - (256 + EE / 256);   // 0..11
        int mat = tb >> 1;               // l*2+m
        int l = mat >> 1, m = mat & 1;
        int kbase = (tb & 1) * 64;
        const float* W = (m == 0 ? Ws : Wn) + (size_t)l * 16384;
        const float4* Wv = (const float4*)(W + (size_t)kbase * 128);
        float4* tv = (float4*)smemF;
#pragma unroll
        for (int r2 = 0; r2 < 8; r2++) tv[r2 * 256 + t] = Wv[r2 * 256 + t];
        __syncthreads();
        int c = t >> 1, seg = t & 1;
        float* dstp = Wt + (size_t)mat * 16384 + (size_t)c * 128 + kbase + seg * 32;
#pragma unroll
        for (int g = 0; g < 8; g++) {
            float4 o4;
            o4.x = smemF[(seg * 32 + g * 4 + 0) * 128 + c];
            o4.y = smemF[(seg * 32 + g * 4 + 1) * 128 + c];
            o4.z = smemF[(seg * 32 + g * 4 + 2) * 128 + c];
            o4.w = smemF[(seg * 32 + g * 4 + 3) * 128 + c];
            *(float4*)&dstp[g * 4] = o4;
        }
    }
}

// ---------- k_layer: fused aggregate (R4-verbatim gather) + dual-GEMM ----------
__launch_bounds__(256, 2)
__global__ void k_layer(const __half* __restrict__ hin, __half* __restrict__ hout,
                        const int* __restrict__ cnt, const unsigned int* __restrict__ buf,
                        const float* __restrict__ WtL,     // [2][128][128] fp32 [c][k]
                        const float* __restrict__ WsRaw,   // [128][128] fp32 (k-major)
                        const float* __restrict__ WnRaw,
                        const float* __restrict__ pstat_l, float* __restrict__ pstatN,
                        const float* __restrict__ gamma, const float* __restrict__ beta,
                        const float* __restrict__ bias,
                        float* __restrict__ sod_g,
                        const float* __restrict__ lin_w, const float* __restrict__ lin_b,
                        float* __restrict__ outv, int firstLayer, int mode) {
    __shared__ __half Bl[128 * 136];      // phase C: B-chunk; epilogue: stats scratch
    __shared__ __half aggLDS[128 * 136];  // raw fp16 agg, fragment-readable
    __shared__ float alF[128], dlF[128];  // fp32 BN scalars
    __shared__ float crL[128], cnL[128];  // fp32 delta-terms (R4's crow/cneigh)
    __shared__ float sodLDS[128];
    __shared__ int dLDS[128];

    int tid = threadIdx.x, lane = tid & 63, wv = tid >> 6;
    int l15 = lane & 15, quad = lane >> 4;
    int i0 = blockIdx.x * 128;

    // ---- phase A1: BN scalars + degrees + sod ----
    if (tid < 128) {
        float mu = pstat_l[tid] * (1.0f / NN);
        float var = pstat_l[128 + tid] * (1.0f / NN) - mu * mu;
        float a = rsqrtf(var + 1e-5f) * gamma[tid];
        float d = beta[tid] - mu * a;
        alF[tid] = a;
        dlF[tid] = d;
        int dd = cnt[(i0 + tid) << CSH];
        dLDS[tid] = dd > CAP ? CAP : dd;
        if (!firstLayer) sodLDS[tid] = sod_g[i0 + tid];
    }
    __syncthreads();

    // ---- phase A2: crow/cneigh in fp32 (exact R4 k_fold math) ----
    if (tid < 128) {
        float cr = bias[tid], cn = 0.f;
        for (int k = 0; k < 128; k++) {
            float dl = dlF[k];
            cr += dl * WsRaw[k * 128 + tid];
            cn += dl * WnRaw[k * 128 + tid];
        }
        crL[tid] = cr;
        cnL[tid] = cn;
    }

    // ---- phase B: gather-aggregate, R4's verbatim shfl-broadcast mechanism ----
    const __half2* hin2 = (const __half2*)hin;
    for (int i = 0; i < 32; i++) {
        int nl = wv * 32 + i;
        int di = dLDS[nl];
        unsigned int pk = 0;
        if (lane < di) pk = buf[(size_t)(i0 + nl) * CAP + lane];
        float ax[8], ay[8];
#pragma unroll
        for (int u = 0; u < 8; u++) { ax[u] = 0.f; ay[u] = 0.f; }
        int rounds = (di + 7) >> 3;
        for (int r = 0; r < rounds; r++) {
            int j = r * 8;
            unsigned int p[8];
            __half2 hv[8];
#pragma unroll
            for (int u = 0; u < 8; u++) p[u] = __shfl(pk, j + u);
#pragma unroll
            for (int u = 0; u < 8; u++)
                hv[u] = hin2[(size_t)(p[u] & 0xFFFFu) * 64 + lane];
#pragma unroll
            for (int u = 0; u < 8; u++) {
                float w = __half2float(__ushort_as_half((unsigned short)(p[u] >> 16)));
                float2 v = __half22float2(hv[u]);
                ax[u] += w * v.x;
                ay[u] += w * v.y;
            }
        }
        float axs = ((ax[0] + ax[1]) + (ax[2] + ax[3])) + ((ax[4] + ax[5]) + (ax[6] + ax[7]));
        float ays = ((ay[0] + ay[1]) + (ay[2] + ay[3])) + ((ay[4] + ay[5]) + (ay[6] + ay[7]));
        float inv = 1.0f / (float)(di > 1 ? di : 1);
        *(__half2*)&aggLDS[nl * 136 + lane * 2] = __floats2half2_rn(axs * inv, ays * inv);
        if (firstLayer) {
            float wl = (lane < di) ? __half2float(__ushort_as_half((unsigned short)(pk >> 16))) : 0.f;
#pragma unroll
            for (int off = 1; off < 64; off <<= 1) wl += __shfl_xor(wl, off);
            if (lane == 0) { float sv = wl * inv; sodLDS[nl] = sv; sod_g[i0 + nl] = sv; }
        }
    }
    __syncthreads();   // aggLDS/sodLDS ready; Bl free for phase C

    // ---- phase C: dual-GEMM, raw fp16 A, B = fp16(alpha_f32 * W_f32) ----
    f32x4 acc0[8], acc1[8];
    f32x4 zero = {0.f, 0.f, 0.f, 0.f};
#pragma unroll
    for (int t2 = 0; t2 < 8; t2++) { acc0[t2] = zero; acc1[t2] = zero; }

#pragma unroll
    for (int chunk = 0; chunk < 2; chunk++) {
        f16x8 af0[4], af1[4];
        if (chunk == 0) {
            size_t r0 = (size_t)(i0 + wv * 32 + l15) * 128;
            size_t r1 = (size_t)(i0 + wv * 32 + 16 + l15) * 128;
#pragma unroll
            for (int s = 0; s < 4; s++) {
                int kof = s * 32 + quad * 8;
                af0[s] = *(const f16x8*)&hin[r0 + kof];
                af1[s] = *(const f16x8*)&hin[r1 + kof];
            }
        } else {
#pragma unroll
            for (int s = 0; s < 4; s++) {
                int kof = s * 32 + quad * 8;
                af0[s] = *(const f16x8*)&aggLDS[(wv * 32 + l15) * 136 + kof];
                af1[s] = *(const f16x8*)&aggLDS[(wv * 32 + 16 + l15) * 136 + kof];
            }
        }
        __syncthreads();   // previous Bl readers done
        const float* Wsrc = WtL + (size_t)chunk * 16384;
#pragma unroll
        for (int it = 0; it < 8; it++) {
            int m = tid * 8 + it * 2048;
            int c = m >> 7, kl = m & 127;
            float4 w0 = *(const float4*)&Wsrc[c * 128 + kl];
            float4 w1 = *(const float4*)&Wsrc[c * 128 + kl + 4];
            float4 a0 = *(const float4*)&alF[kl];
            float4 a1 = *(const float4*)&alF[kl + 4];
            f16x8 o;
            o[0] = (_Float16)(a0.x * w0.x); o[1] = (_Float16)(a0.y * w0.y);
            o[2] = (_Float16)(a0.z * w0.z); o[3] = (_Float16)(a0.w * w0.w);
            o[4] = (_Float16)(a1.x * w1.x); o[5] = (_Float16)(a1.y * w1.y);
            o[6] = (_Float16)(a1.z * w1.z); o[7] = (_Float16)(a1.w * w1.w);
            *(f16x8*)&Bl[c * 136 + kl] = o;
        }
        __syncthreads();
#pragma unroll
        for (int s = 0; s < 4; s++) {
#pragma unroll
            for (int tn = 0; tn < 8; tn++) {
                f16x8 bf = *(const f16x8*)&Bl[(tn * 16 + l15) * 136 + s * 32 + quad * 8];
                acc0[tn] = __builtin_amdgcn_mfma_f32_16x16x32_f16(af0[s], bf, acc0[tn], 0, 0, 0);
                acc1[tn] = __builtin_amdgcn_mfma_f32_16x16x32_f16(af1[s], bf, acc1[tn], 0, 0, 0);
            }
        }
    }

    // ---- epilogue: v = acc + crow + sod*cneigh (fp32), relu ----
    float cr[8], cn[8];
#pragma unroll
    for (int tn = 0; tn < 8; tn++) {
        cr[tn] = crL[tn * 16 + l15];
        cn[tn] = cnL[tn * 16 + l15];
    }
    int lr = wv * 32 + quad * 4;       // local row base
    int rwbase = i0 + lr;

    if (mode == 0) {
        float cs[8], cq[8];
#pragma unroll
        for (int tn = 0; tn < 8; tn++) { cs[tn] = 0.f; cq[tn] = 0.f; }
#pragma unroll
        for (int tm = 0; tm < 2; tm++) {
#pragma unroll
            for (int r = 0; r < 4; r++) {
                int row = rwbase + tm * 16 + r;
                float sdv = sodLDS[lr + tm * 16 + r];
#pragma unroll
                for (int tn = 0; tn < 8; tn++) {
                    float v = (tm ? acc1[tn][r] : acc0[tn][r]) + cr[tn] + sdv * cn[tn];
                    v = fmaxf(v, 0.f);
                    hout[(size_t)row * 128 + tn * 16 + l15] = __float2half(v);
                    cs[tn] += v;
                    cq[tn] += v * v;
                }
            }
        }
#pragma unroll
        for (int tn = 0; tn < 8; tn++) {
            cs[tn] += __shfl_xor(cs[tn], 16); cs[tn] += __shfl_xor(cs[tn], 32);
            cq[tn] += __shfl_xor(cq[tn], 16); cq[tn] += __shfl_xor(cq[tn], 32);
        }
        __syncthreads();
        float* st = (float*)Bl;
        st[tid] = 0.f;
        __syncthreads();
        if (lane < 16) {
#pragma unroll
            for (int tn = 0; tn < 8; tn++) {
                atomicAdd(&st[tn * 16 + l15], cs[tn]);
                atomicAdd(&st[128 + tn * 16 + l15], cq[tn]);
            }
        }
        __syncthreads();
        if (tid < 128) {
            atomicAdd(&pstatN[tid], st[tid]);
            atomicAdd(&pstatN[128 + tid], st[128 + tid]);
        }
    } else {
        float lw[8];
#pragma unroll
        for (int tn = 0; tn < 8; tn++) lw[tn] = lin_w[tn * 16 + l15];
        float lb = lin_b[0];
#pragma unroll
        for (int tm = 0; tm < 2; tm++) {
#pragma unroll
            for (int r = 0; r < 4; r++) {
                int row = rwbase + tm * 16 + r;
                float sdv = sodLDS[lr + tm * 16 + r];
                float p = 0.f;
#pragma unroll
                for (int tn = 0; tn < 8; tn++) {
                    float v = (tm ? acc1[tn][r] : acc0[tn][r]) + cr[tn] + sdv * cn[tn];
                    v = fmaxf(v, 0.f);
                    p += v * lw[tn];
                }
                p += __shfl_xor(p, 1);
                p += __shfl_xor(p, 2);
                p += __shfl_xor(p, 4);
                p += __shfl_xor(p, 8);
                if (l15 == 0) outv[row] = p + lb;
            }
        }
    }
}

// ---------- host ----------

extern "C" void kernel_launch(void* const* d_in, const int* in_sizes, int n_in,
                              void* d_out, int out_size, void* d_ws, size_t ws_size,
                              hipStream_t stream) {
    (void)in_sizes; (void)n_in; (void)out_size; (void)ws_size;
    const float* x     = (const float*)d_in[0];
    const float* ew    = (const float*)d_in[1];
    const float* gamma = (const float*)d_in[2];
    const float* beta  = (const float*)d_in[3];
    const float* Ws    = (const float*)d_in[4];
    const float* Wn    = (const float*)d_in[5];
    const float* bias  = (const float*)d_in[6];
    const float* lin_w = (const float*)d_in[7];
    const float* lin_b = (const float*)d_in[8];
    const int*   srcI  = (const int*)d_in[9];
    const int*   dstI  = (const int*)d_in[10];
    float* out = (float*)d_out;

    char* p = (char*)d_ws;
    __half* h0  = (__half*)p; p += (size_t)NN * CC * 2;
    __half* h1  = (__half*)p; p += (size_t)NN * CC * 2;
    float*  Wt  = (float*)p;  p += (size_t)6 * 128 * 128 * 4;
    float*  sod = (float*)p;  p += (size_t)NN * 4;
    unsigned int* buf = (unsigned int*)p; p += (size_t)NN * CAP * 4;
    // ---- contiguous zero region ----
    int*   cnt   = (int*)p;   p += (size_t)NN * 4 * 16;   // padded: 1 counter / 64B line
    float* pstat = (float*)p; p += 3 * 256 * 4;

    hipMemsetAsync(cnt, 0, (size_t)NN * 64 + 3 * 256 * 4, stream);

    k_init<<<dim3(256 + EE / 256 + 12), dim3(256), 0, stream>>>(
        x, h0, pstat, srcI, dstI, ew, cnt, buf, Ws, Wn, Wt);

    __half* hb[2] = {h0, h1};
    for (int l = 0; l < 3; l++) {
        int mode = (l == 2) ? 1 : 0;
        float* pstatN = (mode == 0) ? (pstat + (l + 1) * 256) : pstat;
        k_layer<<<dim3(NN / 128), dim3(256), 0, stream>>>(
            hb[l & 1], hb[(l + 1) & 1], cnt, buf,
            Wt + (size_t)l * 2 * 16384,
            Ws + (size_t)l * 16384, Wn + (size_t)l * 16384,
            pstat + l * 256, pstatN,
            gamma + l * CC, beta + l * CC, bias + l * CC,
            sod, lin_w, lin_b, out, (l == 0) ? 1 : 0, mode);
    }
}

// Round 9
// 270.990 us; speedup vs baseline: 1.1276x; 1.1276x over previous
//
#include <hip/hip_runtime.h>
#include <hip/hip_fp16.h>

#define NN 65536
#define EE 524288
#define CC 128
#define CAP 40    // bucket capacity; P(deg>=40) ~ 1e-15 at lambda=8
#define CSH 4     // cnt stride shift: 16 ints = one 64B line per counter
#define NA 8192   // agg blocks: 8 nodes per block (4 waves x 2 nodes)

typedef _Float16 f16x8 __attribute__((ext_vector_type(8)));
typedef float f32x4 __attribute__((ext_vector_type(4)));

// ---------- k_init: convert+stats (blocks 0..255) | bucket scatter (256..2303) ----------
__global__ void k_init(const float* __restrict__ x, __half* __restrict__ h,
                       float* __restrict__ pstat0,
                       const int* __restrict__ src, const int* __restrict__ dst,
                       const float* __restrict__ ew,
                       int* __restrict__ cnt, unsigned int* __restrict__ buf) {
    int b = blockIdx.x, t = threadIdx.x;
    if (b < 256) {
        const float4* xv = (const float4*)x;
        __half2* o = (__half2*)h;
        float s[4] = {0, 0, 0, 0}, q[4] = {0, 0, 0, 0};
        for (int k = 0; k < 32; k++) {
            int i = b * 8192 + k * 256 + t;
            float4 v = xv[i];
            o[2 * i]     = __floats2half2_rn(v.x, v.y);
            o[2 * i + 1] = __floats2half2_rn(v.z, v.w);
            s[0] += v.x; s[1] += v.y; s[2] += v.z; s[3] += v.w;
            q[0] += v.x * v.x; q[1] += v.y * v.y; q[2] += v.z * v.z; q[3] += v.w * v.w;
        }
        __shared__ float ls[256];          // [0..127] sum, [128..255] sumsq
        ls[t] = 0.f;
        __syncthreads();
        int c0 = (t & 31) * 4;
#pragma unroll
        for (int u = 0; u < 4; u++) {
            atomicAdd(&ls[c0 + u], s[u]);
            atomicAdd(&ls[128 + c0 + u], q[u]);
        }
        __syncthreads();
        if (t < 128) {
            atomicAdd(&pstat0[t], ls[t]);
            atomicAdd(&pstat0[128 + t], ls[128 + t]);
        }
    } else {
        int e = (b - 256) * 256 + t;
        int d = dst[e];
        int pos = atomicAdd(&cnt[d << CSH], 1);
        float w = log1pf(ew[e]);
        unsigned int pk = (unsigned int)src[e] |
                          ((unsigned int)__half_as_ushort(__float2half(w)) << 16);
        if (pos < CAP) buf[(size_t)d * CAP + pos] = pk;   // guard: never corrupt memory
    }
}

// ---------- k_aggfold: dual-row gather-aggregate | BN fold (last 64 blocks) ----------
// Agg: blocks [0,NA): wave handles 2 nodes; lanes 0-31 = node A, 32-63 = node B.
// Each lane loads uint2 (4 channels); one gather instr covers two 256B rows.
__global__ void k_aggfold(const __half* __restrict__ hin, const int* __restrict__ cnt,
                          const unsigned int* __restrict__ buf,
                          __half* __restrict__ aggn, float* __restrict__ sod, int writeSod,
                          const float* __restrict__ pstat_l,
                          const float* __restrict__ gamma, const float* __restrict__ beta,
                          const float* __restrict__ Ws, const float* __restrict__ Wn,
                          const float* __restrict__ bias,
                          __half* __restrict__ Wcat, float* __restrict__ crow,
                          float* __restrict__ cneigh) {
    int bid = blockIdx.x;
    int tid = threadIdx.x;
    if (bid >= NA) {
        // ---- fold (R4 verbatim): 2 output channels per block ----
        int c = (bid - NA) * 2 + (tid >> 7);
        int k = tid & 127;
        float mu = pstat_l[k] * (1.0f / NN);
        float var = pstat_l[128 + k] * (1.0f / NN) - mu * mu;
        float alpha = rsqrtf(var + 1e-5f) * gamma[k];
        float delta = beta[k] - mu * alpha;
        float ws = Ws[k * 128 + c];
        float wn = Wn[k * 128 + c];
        Wcat[c * 256 + k]       = __float2half(alpha * ws);   // self path
        Wcat[c * 256 + 128 + k] = __float2half(alpha * wn);   // neigh path
        float rs = delta * ws, rn = delta * wn;
#pragma unroll
        for (int off = 1; off < 64; off <<= 1) {
            rs += __shfl_xor(rs, off);
            rn += __shfl_xor(rn, off);
        }
        __shared__ float tmp[8];
        int wvf = tid >> 6;                // wave 0..3
        if ((tid & 63) == 0) { tmp[wvf * 2] = rs; tmp[wvf * 2 + 1] = rn; }
        __syncthreads();
        if ((tid & 127) == 0) {            // tid 0 (c lower) and 128 (c upper)
            int base = (tid >> 7) * 4;
            crow[c]   = bias[c] + tmp[base + 0] + tmp[base + 2];
            cneigh[c] = tmp[base + 1] + tmp[base + 3];
        }
        return;
    }
    // ---- dual-row aggregate ----
    int lane = tid & 63, wv = tid >> 6;
    int lh = lane & 31;                    // lane within half-wave
    int half = lane >> 5;                  // 0 = node A, 1 = node B
    int n = bid * 8 + wv * 2 + half;
    int di = cnt[n << CSH];
    if (di > CAP) di = CAP;
    unsigned int pk = 0;
    if (lh < di) pk = buf[(size_t)n * CAP + lh];   // first min(di,32) records
    const uint2* h2 = (const uint2*)hin;           // 8B units; row r = [r*32, r*32+32)

    float4 ac[8];
#pragma unroll
    for (int u = 0; u < 8; u++) ac[u] = make_float4(0.f, 0.f, 0.f, 0.f);

    int dcl = di > 32 ? 32 : di;
    int rounds = (dcl + 7) >> 3;
    for (int r = 0; r < rounds; r++) {
        int j = r * 8;
        unsigned int p[8];
        uint2 hv[8];
#pragma unroll
        for (int u = 0; u < 8; u++) p[u] = __shfl(pk, half * 32 + j + u);
#pragma unroll
        for (int u = 0; u < 8; u++)
            hv[u] = h2[(size_t)(p[u] & 0xFFFFu) * 32 + lh];
#pragma unroll
        for (int u = 0; u < 8; u++) {
            float w = __half2float(__ushort_as_half((unsigned short)(p[u] >> 16)));
            float2 v0 = __half22float2(*(const __half2*)&hv[u].x);
            float2 v1 = __half22float2(*(const __half2*)&hv[u].y);
            ac[u].x += w * v0.x; ac[u].y += w * v0.y;
            ac[u].z += w * v1.x; ac[u].w += w * v1.y;
        }
    }
    float wrem = 0.f;
    for (int j = 32; j < di; j++) {        // essentially never taken (P ~ 1e-11)
        unsigned int p0 = buf[(size_t)n * CAP + j];
        float w = __half2float(__ushort_as_half((unsigned short)(p0 >> 16)));
        uint2 hv = h2[(size_t)(p0 & 0xFFFFu) * 32 + lh];
        float2 v0 = __half22float2(*(const __half2*)&hv.x);
        float2 v1 = __half22float2(*(const __half2*)&hv.y);
        ac[0].x += w * v0.x; ac[0].y += w * v0.y;
        ac[0].z += w * v1.x; ac[0].w += w * v1.y;
        wrem += w;
    }
    float4 a = make_float4(
        ((ac[0].x + ac[1].x) + (ac[2].x + ac[3].x)) + ((ac[4].x + ac[5].x) + (ac[6].x + ac[7].x)),
        ((ac[0].y + ac[1].y) + (ac[2].y + ac[3].y)) + ((ac[4].y + ac[5].y) + (ac[6].y + ac[7].y)),
        ((ac[0].z + ac[1].z) + (ac[2].z + ac[3].z)) + ((ac[4].z + ac[5].z) + (ac[6].z + ac[7].z)),
        ((ac[0].w + ac[1].w) + (ac[2].w + ac[3].w)) + ((ac[4].w + ac[5].w) + (ac[6].w + ac[7].w)));
    float inv = 1.0f / (float)(di > 1 ? di : 1);
    uint2 outp;
    *(__half2*)&outp.x = __floats2half2_rn(a.x * inv, a.y * inv);
    *(__half2*)&outp.y = __floats2half2_rn(a.z * inv, a.w * inv);
    ((uint2*)aggn)[(size_t)n * 32 + lh] = outp;

    if (writeSod) {
        float wl = (lh < di) ? __half2float(__ushort_as_half((unsigned short)(pk >> 16))) : 0.f;
#pragma unroll
        for (int off = 1; off < 32; off <<= 1) wl += __shfl_xor(wl, off);   // within half-wave
        if (lh == 0) sod[n] = (wl + wrem) * inv;
    }
}

// ---------- k_gemm (R4 verbatim): relu([h | aggn] @ [Ws'; Wn'] + crow + sod*cneigh) ----------
// IN PLACE: hout == hA safe. mode 0: write h_next + next-layer BN stats; mode 1: lin head.
__launch_bounds__(256, 2)
__global__ void k_gemm(const __half* hA, const __half* __restrict__ aggn,
                       const __half* __restrict__ Wcat,
                       const float* __restrict__ crow, const float* __restrict__ cneigh,
                       const float* __restrict__ sod,
                       const float* __restrict__ lin_w, const float* __restrict__ lin_b,
                       __half* hout, float* __restrict__ outv, int mode,
                       float* __restrict__ pstatN) {
    __shared__ __half Bl[128 * 136];   // [c][k_local], stride 136 halves
    int tid = threadIdx.x;
    int lane = tid & 63;
    int wvid = tid >> 6;               // wave 0..3 -> rows [wvid*32, wvid*32+32)
    int l15 = lane & 15, quad = lane >> 4;
    int i0 = blockIdx.x * 128;

    f32x4 acc0[8], acc1[8];
    f32x4 zero = {0.f, 0.f, 0.f, 0.f};
#pragma unroll
    for (int t = 0; t < 8; t++) { acc0[t] = zero; acc1[t] = zero; }

#pragma unroll
    for (int chunk = 0; chunk < 2; chunk++) {
        const __half* Asrc = chunk ? aggn : hA;
        f16x8 af0[4], af1[4];
#pragma unroll
        for (int s = 0; s < 4; s++) {
            int kof = s * 32 + quad * 8;
            af0[s] = *(const f16x8*)&Asrc[(size_t)(i0 + wvid * 32 + l15) * 128 + kof];
            af1[s] = *(const f16x8*)&Asrc[(size_t)(i0 + wvid * 32 + 16 + l15) * 128 + kof];
        }
        __syncthreads();   // previous chunk's reads of Bl done
#pragma unroll
        for (int it = 0; it < 8; it++) {
            int m = tid * 8 + it * 2048;         // covers 128x128 chunk
            int c = m >> 7, kl = m & 127;
            *(f16x8*)&Bl[c * 136 + kl] = *(const f16x8*)&Wcat[c * 256 + chunk * 128 + kl];
        }
        __syncthreads();
#pragma unroll
        for (int s = 0; s < 4; s++) {
#pragma unroll
            for (int tn = 0; tn < 8; tn++) {
                f16x8 bf = *(const f16x8*)&Bl[(tn * 16 + l15) * 136 + s * 32 + quad * 8];
                acc0[tn] = __builtin_amdgcn_mfma_f32_16x16x32_f16(af0[s], bf, acc0[tn], 0, 0, 0);
                acc1[tn] = __builtin_amdgcn_mfma_f32_16x16x32_f16(af1[s], bf, acc1[tn], 0, 0, 0);
            }
        }
    }

    float cr[8], cn[8];
#pragma unroll
    for (int tn = 0; tn < 8; tn++) {
        cr[tn] = crow[tn * 16 + l15];
        cn[tn] = cneigh[tn * 16 + l15];
    }
    int rwbase = i0 + wvid * 32 + quad * 4;

    if (mode == 0) {
        float cs[8], cq[8];
#pragma unroll
        for (int tn = 0; tn < 8; tn++) { cs[tn] = 0.f; cq[tn] = 0.f; }
#pragma unroll
        for (int tm = 0; tm < 2; tm++) {
#pragma unroll
            for (int r = 0; r < 4; r++) {
                int row = rwbase + tm * 16 + r;
                float sdv = sod[row];
#pragma unroll
                for (int tn = 0; tn < 8; tn++) {
                    float v = (tm ? acc1[tn][r] : acc0[tn][r]) + cr[tn] + sdv * cn[tn];
                    v = fmaxf(v, 0.f);
                    hout[(size_t)row * 128 + tn * 16 + l15] = __float2half(v);
                    cs[tn] += v;
                    cq[tn] += v * v;
                }
            }
        }
#pragma unroll
        for (int tn = 0; tn < 8; tn++) {
            cs[tn] += __shfl_xor(cs[tn], 16); cs[tn] += __shfl_xor(cs[tn], 32);
            cq[tn] += __shfl_xor(cq[tn], 16); cq[tn] += __shfl_xor(cq[tn], 32);
        }
        __syncthreads();
        float* st = (float*)Bl;            // reuse LDS: [0..127] sum, [128..255] sumsq
        st[tid] = 0.f;
        __syncthreads();
        if (lane < 16) {
#pragma unroll
            for (int tn = 0; tn < 8; tn++) {
                atomicAdd(&st[tn * 16 + l15], cs[tn]);
                atomicAdd(&st[128 + tn * 16 + l15], cq[tn]);
            }
        }
        __syncthreads();
        if (tid < 128) {
            atomicAdd(&pstatN[tid], st[tid]);
            atomicAdd(&pstatN[128 + tid], st[128 + tid]);
        }
    } else {
        float lw[8];
#pragma unroll
        for (int tn = 0; tn < 8; tn++) lw[tn] = lin_w[tn * 16 + l15];
        float lb = lin_b[0];
#pragma unroll
        for (int tm = 0; tm < 2; tm++) {
#pragma unroll
            for (int r = 0; r < 4; r++) {
                int row = rwbase + tm * 16 + r;
                float sdv = sod[row];
                float p = 0.f;
#pragma unroll
                for (int tn = 0; tn < 8; tn++) {
                    float v = (tm ? acc1[tn][r] : acc0[tn][r]) + cr[tn] + sdv * cn[tn];
                    v = fmaxf(v, 0.f);
                    p += v * lw[tn];
                }
                p += __shfl_xor(p, 1);
                p += __shfl_xor(p, 2);
                p += __shfl_xor(p, 4);
                p += __shfl_xor(p, 8);
                if (l15 == 0) outv[row] = p + lb;
            }
        }
    }
}

// ---------- host ----------

extern "C" void kernel_launch(void* const* d_in, const int* in_sizes, int n_in,
                              void* d_out, int out_size, void* d_ws, size_t ws_size,
                              hipStream_t stream) {
    (void)in_sizes; (void)n_in; (void)out_size; (void)ws_size;
    const float* x     = (const float*)d_in[0];
    const float* ew    = (const float*)d_in[1];
    const float* gamma = (const float*)d_in[2];
    const float* beta  = (const float*)d_in[3];
    const float* Ws    = (const float*)d_in[4];
    const float* Wn    = (const float*)d_in[5];
    const float* bias  = (const float*)d_in[6];
    const float* lin_w = (const float*)d_in[7];
    const float* lin_b = (const float*)d_in[8];
    const int*   srcI  = (const int*)d_in[9];
    const int*   dstI  = (const int*)d_in[10];
    float* out = (float*)d_out;

    char* p = (char*)d_ws;
    __half* h    = (__half*)p; p += (size_t)NN * CC * 2;   // in-place across layers
    __half* aggn = (__half*)p; p += (size_t)NN * CC * 2;
    __half* Wcat = (__half*)p; p += 256 * 128 * 2;
    float* crow   = (float*)p; p += 512;
    float* cneigh = (float*)p; p += 512;
    float* sod    = (float*)p; p += (size_t)NN * 4;
    unsigned int* buf = (unsigned int*)p; p += (size_t)NN * CAP * 4;
    // ---- contiguous zero region ----
    int*   cnt   = (int*)p;   p += (size_t)NN * 4 * 16;   // padded: 1 counter / 64B line
    float* pstat = (float*)p; p += 3 * 256 * 4;           // [layer][sum(128)|sumsq(128)]

    hipMemsetAsync(cnt, 0, (size_t)NN * 64 + 3 * 256 * 4, stream);

    k_init<<<dim3(256 + EE / 256), dim3(256), 0, stream>>>(x, h, pstat, srcI, dstI, ew, cnt, buf);

    for (int l = 0; l < 3; l++) {
        k_aggfold<<<dim3(NA + 64), dim3(256), 0, stream>>>(
            h, cnt, buf, aggn, sod, (l == 0) ? 1 : 0,
            pstat + l * 256, gamma + l * CC, beta + l * CC,
            Ws + (size_t)l * CC * CC, Wn + (size_t)l * CC * CC, bias + l * CC,
            Wcat, crow, cneigh);
        int mode = (l == 2) ? 1 : 0;
        float* pstatN = (mode == 0) ? (pstat + (l + 1) * 256) : pstat;
        k_gemm<<<dim3(NN / 128), dim3(256), 0, stream>>>(h, aggn, Wcat, crow, cneigh, sod,
                                                         lin_w, lin_b, h, out, mode, pstatN);
    }
}